// Round 6
// baseline (917.738 us; speedup 1.0000x reference)
//
#include <hip/hip_runtime.h>
#include <stdint.h>

#define JAX_RNG_PARTITIONABLE 1

#define T_LEN 4096
#define N_ROWS 4096
#define N_ELEM (4096u * 4096u)

// ---------------- wavelet filters (db4) ----------------
__constant__ float c_DEC_LO[8] = {
  -0.010597401785069032f, 0.0328830116668852f, 0.030841381835560764f,
  -0.18703481171909309f, -0.027983769416859854f, 0.6308807679298589f,
   0.7148465705529157f, 0.2303778133088965f };
__constant__ float c_DEC_HI[8] = {
  -0.2303778133088965f, 0.7148465705529157f, -0.6308807679298589f,
  -0.027983769416859854f, 0.18703481171909309f, 0.030841381835560764f,
  -0.0328830116668852f, -0.010597401785069032f };
__constant__ float c_REC_LO[8] = {
   0.2303778133088965f, 0.7148465705529157f, 0.6308807679298589f,
  -0.027983769416859854f, -0.18703481171909309f, 0.030841381835560764f,
   0.0328830116668852f, -0.010597401785069032f };
__constant__ float c_REC_HI[8] = {
  -0.010597401785069032f, -0.0328830116668852f, 0.030841381835560764f,
   0.18703481171909309f, -0.027983769416859854f, -0.6308807679298589f,
   0.7148465705529157f, -0.2303778133088965f };

// ---------------- Threefry-2x32 (20 rounds) ----------------
__device__ __forceinline__ uint32_t rotl32(uint32_t v, int r) {
  return (v << r) | (v >> (32 - r));
}

__device__ __forceinline__ void tf2x32(uint32_t k0, uint32_t k1,
                                       uint32_t c0, uint32_t c1,
                                       uint32_t& o0, uint32_t& o1) {
  uint32_t ks2 = k0 ^ k1 ^ 0x1BD11BDAu;
  uint32_t x0 = c0 + k0;
  uint32_t x1 = c1 + k1;
#define TFR(r) { x0 += x1; x1 = rotl32(x1, r); x1 ^= x0; }
  TFR(13) TFR(15) TFR(26) TFR(6)
  x0 += k1;  x1 += ks2 + 1u;
  TFR(17) TFR(29) TFR(16) TFR(24)
  x0 += ks2; x1 += k0 + 2u;
  TFR(13) TFR(15) TFR(26) TFR(6)
  x0 += k0;  x1 += k1 + 3u;
  TFR(17) TFR(29) TFR(16) TFR(24)
  x0 += k1;  x1 += ks2 + 4u;
  TFR(13) TFR(15) TFR(26) TFR(6)
  x0 += ks2; x1 += k0 + 5u;
#undef TFR
  o0 = x0; o1 = x1;
}

__device__ __forceinline__ uint32_t jbits_scalar(uint32_t kx, uint32_t ky) {
  uint32_t a, b; tf2x32(kx, ky, 0u, 0u, a, b);
#if JAX_RNG_PARTITIONABLE
  return a ^ b;
#else
  return a;
#endif
}

__device__ __forceinline__ uint32_t jbits_elem(uint32_t kx, uint32_t ky, uint32_t i) {
#if JAX_RNG_PARTITIONABLE
  uint32_t a, b; tf2x32(kx, ky, 0u, i, a, b); return a ^ b;
#else
  const uint32_t half = N_ELEM / 2u;
  uint32_t a, b;
  if (i < half) { tf2x32(kx, ky, i, i + half, a, b); return a; }
  else          { tf2x32(kx, ky, i - half, i, a, b); return b; }
#endif
}

__device__ __forceinline__ float junif_scalar(uint32_t kx, uint32_t ky) {
  union { uint32_t u; float f; } cv;
  cv.u = (jbits_scalar(kx, ky) >> 9) | 0x3f800000u;
  return cv.f - 1.0f;
}

__device__ __forceinline__ void jsplit2(uint32_t kx, uint32_t ky, uint32_t* o) {
#if JAX_RNG_PARTITIONABLE
  tf2x32(kx, ky, 0u, 0u, o[0], o[1]);
  tf2x32(kx, ky, 0u, 1u, o[2], o[3]);
#else
  uint32_t a0, b0, a1, b1;
  tf2x32(kx, ky, 0u, 2u, a0, b0);
  tf2x32(kx, ky, 1u, 3u, a1, b1);
  o[0] = a0; o[1] = a1; o[2] = b0; o[3] = b1;
#endif
}

__device__ __forceinline__ void jsplit4(uint32_t kx, uint32_t ky, uint32_t* o) {
#if JAX_RNG_PARTITIONABLE
  tf2x32(kx, ky, 0u, 0u, o[0], o[1]);
  tf2x32(kx, ky, 0u, 1u, o[2], o[3]);
  tf2x32(kx, ky, 0u, 2u, o[4], o[5]);
  tf2x32(kx, ky, 0u, 3u, o[6], o[7]);
#else
  uint32_t a0,b0,a1,b1,a2,b2,a3,b3;
  tf2x32(kx, ky, 0u, 4u, a0, b0);
  tf2x32(kx, ky, 1u, 5u, a1, b1);
  tf2x32(kx, ky, 2u, 6u, a2, b2);
  tf2x32(kx, ky, 3u, 7u, a3, b3);
  o[0]=a0; o[1]=a1; o[2]=a2; o[3]=a3; o[4]=b0; o[5]=b1; o[6]=b2; o[7]=b3;
#endif
}

__device__ __forceinline__ int jrandint(uint32_t kx, uint32_t ky, uint32_t span) {
  uint32_t c[4];
  jsplit2(kx, ky, c);
  uint32_t hi = jbits_scalar(c[0], c[1]);
  uint32_t lo = jbits_scalar(c[2], c[3]);
  uint32_t mult = 65536u % span;
  mult = (mult * mult) % span;
  uint32_t off = ((hi % span) * mult + (lo % span)) % span;
  return (int)off;
}

__device__ __forceinline__ float erfinv32(float x) {
  float w = -log1pf(-x * x);
  float p;
  if (w < 5.0f) {
    w = w - 2.5f;
    p = 2.81022636e-08f;
    p = fmaf(p, w, 3.43273939e-07f);
    p = fmaf(p, w, -3.5233877e-06f);
    p = fmaf(p, w, -4.39150654e-06f);
    p = fmaf(p, w, 0.00021858087f);
    p = fmaf(p, w, -0.00125372503f);
    p = fmaf(p, w, -0.00417768164f);
    p = fmaf(p, w, 0.246640727f);
    p = fmaf(p, w, 1.50140941f);
  } else {
    w = sqrtf(w) - 3.0f;
    p = -0.000200214257f;
    p = fmaf(p, w, 0.000100950558f);
    p = fmaf(p, w, 0.00134934322f);
    p = fmaf(p, w, -0.00367342844f);
    p = fmaf(p, w, 0.00573950773f);
    p = fmaf(p, w, -0.0076224613f);
    p = fmaf(p, w, 0.00943887047f);
    p = fmaf(p, w, 1.00167406f);
    p = fmaf(p, w, 2.83297682f);
  }
  return p * x;
}

__device__ __forceinline__ float jax_normal_from_bits(uint32_t bits) {
  union { uint32_t u; float f; } cv;
  cv.u = (bits >> 9) | 0x3f800000u;
  float f = cv.f - 1.0f;
  const float lo = -0.99999994f;
  float u = __fadd_rn(__fmul_rn(f, 2.0f), lo);
  u = fmaxf(lo, u);
  return 1.41421356f * erfinv32(u);
}

// ---------------- params ----------------
struct RngParams {
  uint32_t kn_x, kn_y, kcn_x, kcn_y;
  int f0_d, t0_d, af_d, at_d;
  int f0_c, t0_c, af_c, at_c;
};
__device__ RngParams g_params;

__device__ void distort_params(uint32_t kx, uint32_t ky,
                               int* f0, int* af, int* t0, int* at) {
  uint32_t q[8];
  jsplit4(kx, ky, q);
  *af = junif_scalar(q[0], q[1]) < 0.3f;
  *f0 = jrandint(q[2], q[3], 3687u);
  *at = junif_scalar(q[4], q[5]) < 0.3f;
  *t0 = jrandint(q[6], q[7], 3892u);
}

__global__ void setup_rng_kernel() {
  if (threadIdx.x != 0 || blockIdx.x != 0) return;
  uint32_t r[8];
  jsplit4(0u, 42u, r);  // kd, kn, kcd, kcn
  g_params.kn_x  = r[2]; g_params.kn_y  = r[3];
  g_params.kcn_x = r[6]; g_params.kcn_y = r[7];
  distort_params(r[0], r[1], &g_params.f0_d, &g_params.af_d, &g_params.t0_d, &g_params.at_d);
  distort_params(r[4], r[5], &g_params.f0_c, &g_params.af_c, &g_params.t0_c, &g_params.at_c);
}

// ---------------- numpy pairwise f32 sum (exact replica, n in [8,128]) ----------------
__device__ float np_pw_block(const float* a, int n) {
  float r0 = a[0], r1 = a[1], r2 = a[2], r3 = a[3];
  float r4 = a[4], r5 = a[5], r6 = a[6], r7 = a[7];
  int nmain = n - (n & 7);
  int i;
  for (i = 8; i < nmain; i += 8) {
    r0 = __fadd_rn(r0, a[i + 0]); r1 = __fadd_rn(r1, a[i + 1]);
    r2 = __fadd_rn(r2, a[i + 2]); r3 = __fadd_rn(r3, a[i + 3]);
    r4 = __fadd_rn(r4, a[i + 4]); r5 = __fadd_rn(r5, a[i + 5]);
    r6 = __fadd_rn(r6, a[i + 6]); r7 = __fadd_rn(r7, a[i + 7]);
  }
  float res = __fadd_rn(
      __fadd_rn(__fadd_rn(r0, r1), __fadd_rn(r2, r3)),
      __fadd_rn(__fadd_rn(r4, r5), __fadd_rn(r6, r7)));
  for (; i < n; ++i) res = __fadd_rn(res, a[i]);
  return res;
}

// numpy pairwise_sum for n=262: split 128 | (64 | 70)
__device__ float np_pw_sum262(const float* a) {
  float left  = np_pw_block(a, 128);
  float l2    = np_pw_block(a + 128, 64);
  float r2    = np_pw_block(a + 192, 70);
  return __fadd_rn(left, __fadd_rn(l2, r2));
}

// numpy tree-of-8 sum (pairwise_sum at exactly n=8)
__device__ __forceinline__ float tree8(const float* p) {
  return __fadd_rn(
      __fadd_rn(__fadd_rn(p[0], p[1]), __fadd_rn(p[2], p[3])),
      __fadd_rn(__fadd_rn(p[4], p[5]), __fadd_rn(p[6], p[7])));
}

// ---------------- wavelet (f32, tree-of-8 conv accumulation) ----------------
__device__ void dwt_step(const float* a, int n, float* oa, float* od, int nOut, int tid) {
  for (int i = tid; i < nOut; i += 256) {
    int base = 2 * i - 6;
    float pa[8], pd[8];
    #pragma unroll
    for (int j = 0; j < 8; ++j) {
      int q = base + j;
      q = (q < 0) ? (-q - 1) : ((q >= n) ? (2 * n - 1 - q) : q);
      float xv = a[q];
      pa[j] = __fmul_rn(c_DEC_LO[7 - j], xv);
      pd[j] = __fmul_rn(c_DEC_HI[7 - j], xv);
    }
    oa[i] = tree8(pa);
    od[i] = tree8(pd);
  }
}

__device__ void idwt_step(const float* a, const float* d, int m, float* out,
                          float thr, int tid) {
  int nOut = 2 * m - 6;
  for (int t = tid; t < nOut; t += 256) {
    float pa[8], pd[8];
    #pragma unroll
    for (int jj = 0; jj < 8; ++jj) {
      int q = t - 1 + jj;
      float va = 0.f, vd = 0.f;
      if ((q & 1) == 0) {
        int h = q >> 1;
        if (h >= 0 && h < m) {
          va = __fmul_rn(c_REC_LO[7 - jj], a[h]);
          float dv = d[h];
          dv = (fabsf(dv) < thr) ? 0.f : dv;
          vd = __fmul_rn(c_REC_HI[7 - jj], dv);
        }
      }
      pa[jj] = va; pd[jj] = vd;
    }
    out[t] = __fadd_rn(tree8(pa), tree8(pd));
  }
}

__global__ __launch_bounds__(256)
void wavelet_kernel(const float* __restrict__ x, float* __restrict__ out0,
                    float* __restrict__ out1, float* __restrict__ out4) {
  __shared__ float A[4096];
  __shared__ float B[4096];
  __shared__ float D1[2051];
  __shared__ float D2[1029];
  __shared__ float D3[518];
  __shared__ float D4[262];
  __shared__ float A4[262];
  __shared__ float SQ[262];
  __shared__ float s_sigma;
  const int row = blockIdx.x, tid = threadIdx.x;
  const float* s = x + (size_t)row * T_LEN;
  for (int i = tid; i < T_LEN; i += 256) {
    float v = s[i];
    A[i] = v;
    out0[(size_t)row * T_LEN + i] = v;  // out0 = x
  }
  __syncthreads();
  dwt_step(A, 4096, B, D1, 2051, tid); __syncthreads();
  dwt_step(B, 2051, A, D2, 1029, tid); __syncthreads();
  dwt_step(A, 1029, B, D3, 518, tid);  __syncthreads();
  dwt_step(B, 518, A4, D4, 262, tid);  __syncthreads();

  // std(a4), ddof=0 — exact numpy pairwise-f32 semantics (ref=np)
  if (tid == 0) {
    float sum = np_pw_sum262(A4);
    float mu = sum / 262.0f;
    for (int i = 0; i < 262; ++i) {
      float dv = __fsub_rn(A4[i], mu);
      SQ[i] = __fmul_rn(dv, dv);
    }
    float ssd = np_pw_sum262(SQ);
    s_sigma = __fsqrt_rn(ssd / 262.0f);
  }
  __syncthreads();
  float sigma = s_sigma;

  for (int v = 0; v < 2; ++v) {
    float thr = __fmul_rn((v == 0 ? 0.5f : 0.25f), sigma);
    for (int i = tid; i < 262; i += 256) {
      float c = A4[i];
      A[i] = (fabsf(c) < thr) ? 0.f : c;
    }
    __syncthreads();
    idwt_step(A, D4, 262, B, thr, tid);  __syncthreads();  // 518
    idwt_step(B, D3, 518, A, thr, tid);  __syncthreads();  // 1030 (use 1029)
    idwt_step(A, D2, 1029, B, thr, tid); __syncthreads();  // 2052 (use 2051)
    idwt_step(B, D1, 2051, A, thr, tid); __syncthreads();  // 4096
    float* dst = (v == 0 ? out1 : out4) + (size_t)row * T_LEN;
    for (int i = tid; i < T_LEN; i += 256) dst[i] = A[i];
    __syncthreads();
  }
}

// ---------------- spectral distortion (FFT) ----------------
__device__ void fft4096(float2* A, float2* B, int tid, float sgn) {
  float2* sB = A; float2* dB = B;
  int lgm = 0;
  int l = 2048;
  for (int st = 0; st < 12; ++st) {
    float ang0 = sgn * 3.14159265358979f / (float)l;
    int m = 1 << lgm;
    for (int u = tid; u < 2048; u += 256) {
      int j = u >> lgm;
      float2 c0 = sB[u];
      float2 c1 = sB[u + 2048];
      float sx = c0.x + c1.x, sy = c0.y + c1.y;
      float dx = c0.x - c1.x, dy = c0.y - c1.y;
      float th = ang0 * (float)j;
      float sn, cs;
      sincosf(th, &sn, &cs);
      int ob = u + (j << lgm);
      dB[ob].x = sx; dB[ob].y = sy;
      dB[ob + m].x = cs * dx - sn * dy;
      dB[ob + m].y = cs * dy + sn * dx;
    }
    __syncthreads();
    float2* t = sB; sB = dB; dB = t;
    l >>= 1; lgm++;
  }
}

__global__ __launch_bounds__(256)
void distort_kernel(const float* src, float* dst, int which) {
  extern __shared__ float2 sh[];
  float2* A = sh;
  float2* B = sh + 4096;
  const int row = blockIdx.x, tid = threadIdx.x;
  const int f0 = which ? g_params.f0_c : g_params.f0_d;
  const int af = which ? g_params.af_c : g_params.af_d;
  const int t0 = which ? g_params.t0_c : g_params.t0_d;
  const int at = which ? g_params.at_c : g_params.at_d;
  const float* s = src + (size_t)row * T_LEN;
  float* d = dst + (size_t)row * T_LEN;

  if (!af) {
    for (int i = tid; i < T_LEN; i += 256) {
      float v = s[i];
      if (at && i >= t0 && i < t0 + 204) v *= 0.1f;
      d[i] = v;
    }
    return;
  }

  for (int i = tid; i < T_LEN; i += 256) { A[i].x = s[i]; A[i].y = 0.f; }
  __syncthreads();
  fft4096(A, B, tid, -1.0f);
  for (int k = tid; k < T_LEN; k += 256) {
    if (k >= f0 && k < f0 + 409) { A[k].x *= 0.1f; A[k].y *= 0.1f; }
  }
  __syncthreads();
  fft4096(A, B, tid, 1.0f);
  for (int i = tid; i < T_LEN; i += 256) {
    float vv = A[i].x * (1.0f / 4096.0f);
    if (at && i >= t0 && i < t0 + 204) vv *= 0.1f;
    d[i] = vv;
  }
}

// ---------------- additive noise ----------------
__global__ __launch_bounds__(256)
void noise_kernel(const float* src, float* dst, int which) {
  __shared__ float red[256];
  const int row = blockIdx.x, tid = threadIdx.x;
  const float* s = src + (size_t)row * T_LEN;
  float v[16];
  float acc = 0.f;
  #pragma unroll
  for (int i = 0; i < 16; ++i) { v[i] = s[tid + (i << 8)]; acc += v[i]; }
  red[tid] = acc; __syncthreads();
  for (int o = 128; o > 0; o >>= 1) { if (tid < o) red[tid] += red[tid + o]; __syncthreads(); }
  float mu = red[0] * (1.0f / 4096.0f);
  __syncthreads();
  acc = 0.f;
  #pragma unroll
  for (int i = 0; i < 16; ++i) { float dv = v[i] - mu; acc += dv * dv; }
  red[tid] = acc; __syncthreads();
  for (int o = 128; o > 0; o >>= 1) { if (tid < o) red[tid] += red[tid + o]; __syncthreads(); }
  float sigma = sqrtf(red[0] / 4095.0f);  // ddof=1

  uint32_t kx = which ? g_params.kcn_x : g_params.kn_x;
  uint32_t ky = which ? g_params.kcn_y : g_params.kn_y;
  float* d = dst + (size_t)row * T_LEN;
  #pragma unroll
  for (int i = 0; i < 16; ++i) {
    uint32_t col = (uint32_t)(tid + (i << 8));
    uint32_t idx = ((uint32_t)row << 12) + col;
    float z = jax_normal_from_bits(jbits_elem(kx, ky, idx));
    d[col] = v[i] + __fmul_rn(__fmul_rn(z, 0.02f), sigma);
  }
}

// ---------------- launcher ----------------
extern "C" void kernel_launch(void* const* d_in, const int* in_sizes, int n_in,
                              void* d_out, int out_size, void* d_ws, size_t ws_size,
                              hipStream_t stream) {
  const float* x = (const float*)d_in[0];
  float* out = (float*)d_out;
  float* o0 = out;
  float* o1 = out + (size_t)N_ELEM;
  float* o2 = out + 2 * (size_t)N_ELEM;
  float* o3 = out + 3 * (size_t)N_ELEM;
  float* o4 = out + 4 * (size_t)N_ELEM;

  hipLaunchKernelGGL(setup_rng_kernel, dim3(1), dim3(64), 0, stream);
  hipLaunchKernelGGL(wavelet_kernel, dim3(N_ROWS), dim3(256), 0, stream, x, o0, o1, o4);
  hipLaunchKernelGGL(distort_kernel, dim3(N_ROWS), dim3(256), 65536, stream, x, o2, 0);
  hipLaunchKernelGGL(distort_kernel, dim3(N_ROWS), dim3(256), 65536, stream, o4, o4, 1);
  hipLaunchKernelGGL(noise_kernel, dim3(N_ROWS), dim3(256), 0, stream, x, o3, 0);
  hipLaunchKernelGGL(noise_kernel, dim3(N_ROWS), dim3(256), 0, stream, o4, o4, 1);
}

// Round 7
// 454.106 us; speedup vs baseline: 2.0210x; 2.0210x over previous
//
#include <hip/hip_runtime.h>
#include <stdint.h>

#define JAX_RNG_PARTITIONABLE 1

#define T_LEN 4096
#define N_ROWS 4096
#define N_ELEM (4096u * 4096u)

// ---------------- wavelet filters (db4) ----------------
__constant__ float c_DEC_LO[8] = {
  -0.010597401785069032f, 0.0328830116668852f, 0.030841381835560764f,
  -0.18703481171909309f, -0.027983769416859854f, 0.6308807679298589f,
   0.7148465705529157f, 0.2303778133088965f };
__constant__ float c_DEC_HI[8] = {
  -0.2303778133088965f, 0.7148465705529157f, -0.6308807679298589f,
  -0.027983769416859854f, 0.18703481171909309f, 0.030841381835560764f,
  -0.0328830116668852f, -0.010597401785069032f };

// REC_LO/REC_HI as compile-time literals (used via parity ternaries in idwt)
#define RL0 0.2303778133088965f
#define RL1 0.7148465705529157f
#define RL2 0.6308807679298589f
#define RL3 (-0.027983769416859854f)
#define RL4 (-0.18703481171909309f)
#define RL5 0.030841381835560764f
#define RL6 0.0328830116668852f
#define RL7 (-0.010597401785069032f)
#define RH0 (-0.010597401785069032f)
#define RH1 (-0.0328830116668852f)
#define RH2 0.030841381835560764f
#define RH3 0.18703481171909309f
#define RH4 (-0.027983769416859854f)
#define RH5 (-0.6308807679298589f)
#define RH6 0.7148465705529157f
#define RH7 (-0.2303778133088965f)

// ---------------- Threefry-2x32 (20 rounds) ----------------
__device__ __forceinline__ uint32_t rotl32(uint32_t v, int r) {
  return (v << r) | (v >> (32 - r));
}

__device__ __forceinline__ void tf2x32(uint32_t k0, uint32_t k1,
                                       uint32_t c0, uint32_t c1,
                                       uint32_t& o0, uint32_t& o1) {
  uint32_t ks2 = k0 ^ k1 ^ 0x1BD11BDAu;
  uint32_t x0 = c0 + k0;
  uint32_t x1 = c1 + k1;
#define TFR(r) { x0 += x1; x1 = rotl32(x1, r); x1 ^= x0; }
  TFR(13) TFR(15) TFR(26) TFR(6)
  x0 += k1;  x1 += ks2 + 1u;
  TFR(17) TFR(29) TFR(16) TFR(24)
  x0 += ks2; x1 += k0 + 2u;
  TFR(13) TFR(15) TFR(26) TFR(6)
  x0 += k0;  x1 += k1 + 3u;
  TFR(17) TFR(29) TFR(16) TFR(24)
  x0 += k1;  x1 += ks2 + 4u;
  TFR(13) TFR(15) TFR(26) TFR(6)
  x0 += ks2; x1 += k0 + 5u;
#undef TFR
  o0 = x0; o1 = x1;
}

__device__ __forceinline__ uint32_t jbits_scalar(uint32_t kx, uint32_t ky) {
  uint32_t a, b; tf2x32(kx, ky, 0u, 0u, a, b);
#if JAX_RNG_PARTITIONABLE
  return a ^ b;
#else
  return a;
#endif
}

__device__ __forceinline__ uint32_t jbits_elem(uint32_t kx, uint32_t ky, uint32_t i) {
#if JAX_RNG_PARTITIONABLE
  uint32_t a, b; tf2x32(kx, ky, 0u, i, a, b); return a ^ b;
#else
  const uint32_t half = N_ELEM / 2u;
  uint32_t a, b;
  if (i < half) { tf2x32(kx, ky, i, i + half, a, b); return a; }
  else          { tf2x32(kx, ky, i - half, i, a, b); return b; }
#endif
}

__device__ __forceinline__ float junif_scalar(uint32_t kx, uint32_t ky) {
  union { uint32_t u; float f; } cv;
  cv.u = (jbits_scalar(kx, ky) >> 9) | 0x3f800000u;
  return cv.f - 1.0f;
}

__device__ __forceinline__ void jsplit2(uint32_t kx, uint32_t ky, uint32_t* o) {
#if JAX_RNG_PARTITIONABLE
  tf2x32(kx, ky, 0u, 0u, o[0], o[1]);
  tf2x32(kx, ky, 0u, 1u, o[2], o[3]);
#else
  uint32_t a0, b0, a1, b1;
  tf2x32(kx, ky, 0u, 2u, a0, b0);
  tf2x32(kx, ky, 1u, 3u, a1, b1);
  o[0] = a0; o[1] = a1; o[2] = b0; o[3] = b1;
#endif
}

__device__ __forceinline__ void jsplit4(uint32_t kx, uint32_t ky, uint32_t* o) {
#if JAX_RNG_PARTITIONABLE
  tf2x32(kx, ky, 0u, 0u, o[0], o[1]);
  tf2x32(kx, ky, 0u, 1u, o[2], o[3]);
  tf2x32(kx, ky, 0u, 2u, o[4], o[5]);
  tf2x32(kx, ky, 0u, 3u, o[6], o[7]);
#else
  uint32_t a0,b0,a1,b1,a2,b2,a3,b3;
  tf2x32(kx, ky, 0u, 4u, a0, b0);
  tf2x32(kx, ky, 1u, 5u, a1, b1);
  tf2x32(kx, ky, 2u, 6u, a2, b2);
  tf2x32(kx, ky, 3u, 7u, a3, b3);
  o[0]=a0; o[1]=a1; o[2]=a2; o[3]=a3; o[4]=b0; o[5]=b1; o[6]=b2; o[7]=b3;
#endif
}

__device__ __forceinline__ int jrandint(uint32_t kx, uint32_t ky, uint32_t span) {
  uint32_t c[4];
  jsplit2(kx, ky, c);
  uint32_t hi = jbits_scalar(c[0], c[1]);
  uint32_t lo = jbits_scalar(c[2], c[3]);
  uint32_t mult = 65536u % span;
  mult = (mult * mult) % span;
  uint32_t off = ((hi % span) * mult + (lo % span)) % span;
  return (int)off;
}

__device__ __forceinline__ float erfinv32(float x) {
  float w = -log1pf(-x * x);
  float p;
  if (w < 5.0f) {
    w = w - 2.5f;
    p = 2.81022636e-08f;
    p = fmaf(p, w, 3.43273939e-07f);
    p = fmaf(p, w, -3.5233877e-06f);
    p = fmaf(p, w, -4.39150654e-06f);
    p = fmaf(p, w, 0.00021858087f);
    p = fmaf(p, w, -0.00125372503f);
    p = fmaf(p, w, -0.00417768164f);
    p = fmaf(p, w, 0.246640727f);
    p = fmaf(p, w, 1.50140941f);
  } else {
    w = sqrtf(w) - 3.0f;
    p = -0.000200214257f;
    p = fmaf(p, w, 0.000100950558f);
    p = fmaf(p, w, 0.00134934322f);
    p = fmaf(p, w, -0.00367342844f);
    p = fmaf(p, w, 0.00573950773f);
    p = fmaf(p, w, -0.0076224613f);
    p = fmaf(p, w, 0.00943887047f);
    p = fmaf(p, w, 1.00167406f);
    p = fmaf(p, w, 2.83297682f);
  }
  return p * x;
}

__device__ __forceinline__ float jax_normal_from_bits(uint32_t bits) {
  union { uint32_t u; float f; } cv;
  cv.u = (bits >> 9) | 0x3f800000u;
  float f = cv.f - 1.0f;
  const float lo = -0.99999994f;
  float u = __fadd_rn(__fmul_rn(f, 2.0f), lo);
  u = fmaxf(lo, u);
  return 1.41421356f * erfinv32(u);
}

// ---------------- params ----------------
struct RngParams {
  uint32_t kn_x, kn_y, kcn_x, kcn_y;
  int f0_d, t0_d, af_d, at_d;
  int f0_c, t0_c, af_c, at_c;
};
__device__ RngParams g_params;

__device__ void distort_params(uint32_t kx, uint32_t ky,
                               int* f0, int* af, int* t0, int* at) {
  uint32_t q[8];
  jsplit4(kx, ky, q);
  *af = junif_scalar(q[0], q[1]) < 0.3f;
  *f0 = jrandint(q[2], q[3], 3687u);
  *at = junif_scalar(q[4], q[5]) < 0.3f;
  *t0 = jrandint(q[6], q[7], 3892u);
}

__global__ void setup_rng_kernel() {
  if (threadIdx.x != 0 || blockIdx.x != 0) return;
  uint32_t r[8];
  jsplit4(0u, 42u, r);  // kd, kn, kcd, kcn
  g_params.kn_x  = r[2]; g_params.kn_y  = r[3];
  g_params.kcn_x = r[6]; g_params.kcn_y = r[7];
  distort_params(r[0], r[1], &g_params.f0_d, &g_params.af_d, &g_params.t0_d, &g_params.at_d);
  distort_params(r[4], r[5], &g_params.f0_c, &g_params.af_c, &g_params.t0_c, &g_params.at_c);
}

// ---------------- numpy pairwise f32 block sum (exact replica, n in [8,128]) ----------------
__device__ float np_pw_block(const float* a, int n) {
  float r0 = a[0], r1 = a[1], r2 = a[2], r3 = a[3];
  float r4 = a[4], r5 = a[5], r6 = a[6], r7 = a[7];
  int nmain = n - (n & 7);
  int i;
  for (i = 8; i < nmain; i += 8) {
    r0 = __fadd_rn(r0, a[i + 0]); r1 = __fadd_rn(r1, a[i + 1]);
    r2 = __fadd_rn(r2, a[i + 2]); r3 = __fadd_rn(r3, a[i + 3]);
    r4 = __fadd_rn(r4, a[i + 4]); r5 = __fadd_rn(r5, a[i + 5]);
    r6 = __fadd_rn(r6, a[i + 6]); r7 = __fadd_rn(r7, a[i + 7]);
  }
  float res = __fadd_rn(
      __fadd_rn(__fadd_rn(r0, r1), __fadd_rn(r2, r3)),
      __fadd_rn(__fadd_rn(r4, r5), __fadd_rn(r6, r7)));
  for (; i < n; ++i) res = __fadd_rn(res, a[i]);
  return res;
}

// numpy tree-of-8 sum (pairwise_sum at exactly n=8)
__device__ __forceinline__ float tree8(const float* p) {
  return __fadd_rn(
      __fadd_rn(__fadd_rn(p[0], p[1]), __fadd_rn(p[2], p[3])),
      __fadd_rn(__fadd_rn(p[4], p[5]), __fadd_rn(p[6], p[7])));
}

// ---------------- wavelet (f32, tree-of-8 conv accumulation — bit-exact vs round 6) ----------------
__device__ void dwt_step(const float* a, int n, float* oa, float* od, int nOut, int tid) {
  int iHi = (n - 2) >> 1;  // interior: base >= 0 and base+7 <= n-1
  for (int i = tid; i < nOut; i += 256) {
    int base = 2 * i - 6;
    float pa[8], pd[8];
    if (i >= 3 && i <= iHi) {
      #pragma unroll
      for (int j = 0; j < 8; ++j) {
        float xv = a[base + j];
        pa[j] = __fmul_rn(c_DEC_LO[7 - j], xv);
        pd[j] = __fmul_rn(c_DEC_HI[7 - j], xv);
      }
    } else {
      #pragma unroll
      for (int j = 0; j < 8; ++j) {
        int q = base + j;
        q = (q < 0) ? (-q - 1) : ((q >= n) ? (2 * n - 1 - q) : q);
        float xv = a[q];
        pa[j] = __fmul_rn(c_DEC_LO[7 - j], xv);
        pd[j] = __fmul_rn(c_DEC_HI[7 - j], xv);
      }
    }
    oa[i] = tree8(pa);
    od[i] = tree8(pd);
  }
}

// Parity-split idwt: for each t only 4 taps are nonzero; dropping the zero
// slots from tree8 is FP-exact (x + 0.0f == x; only ±0 sign can differ).
__device__ void idwt_step(const float* __restrict__ a, const float* __restrict__ d,
                          int m, float* __restrict__ out, float thr, int tid) {
  int nOut = 2 * m - 6;
  for (int t = tid; t < nOut; t += 256) {
    int odd = t & 1;
    int h0 = (t - odd) >> 1;
    float a0 = a[h0], a1 = a[h0 + 1], a2 = a[h0 + 2], a3 = a[h0 + 3];
    float d0 = d[h0], d1 = d[h0 + 1], d2 = d[h0 + 2], d3 = d[h0 + 3];
    d0 = (fabsf(d0) < thr) ? 0.f : d0;
    d1 = (fabsf(d1) < thr) ? 0.f : d1;
    d2 = (fabsf(d2) < thr) ? 0.f : d2;
    d3 = (fabsf(d3) < thr) ? 0.f : d3;
    float cl0 = odd ? RL7 : RL6, cl1 = odd ? RL5 : RL4;
    float cl2 = odd ? RL3 : RL2, cl3 = odd ? RL1 : RL0;
    float ch0 = odd ? RH7 : RH6, ch1 = odd ? RH5 : RH4;
    float ch2 = odd ? RH3 : RH2, ch3 = odd ? RH1 : RH0;
    float sa = __fadd_rn(__fadd_rn(__fmul_rn(cl0, a0), __fmul_rn(cl1, a1)),
                         __fadd_rn(__fmul_rn(cl2, a2), __fmul_rn(cl3, a3)));
    float sd = __fadd_rn(__fadd_rn(__fmul_rn(ch0, d0), __fmul_rn(ch1, d1)),
                         __fadd_rn(__fmul_rn(ch2, d2), __fmul_rn(ch3, d3)));
    out[t] = __fadd_rn(sa, sd);
  }
}

__global__ __launch_bounds__(256)
void wavelet_kernel(const float* __restrict__ x, float* __restrict__ out0,
                    float* __restrict__ out1, float* __restrict__ out4) {
  __shared__ __align__(16) float A[4096];
  __shared__ __align__(16) float B[4096];
  __shared__ float D1[2051];
  __shared__ float D2[1029];
  __shared__ float D3[518];
  __shared__ float D4[262];
  __shared__ float A4[262];
  __shared__ float SQ[262];
  __shared__ float sb[3];
  __shared__ float s_mu, s_sigma;
  const int row = blockIdx.x, tid = threadIdx.x;
  const float4* s4 = reinterpret_cast<const float4*>(x + (size_t)row * T_LEN);
  float4* o04 = reinterpret_cast<float4*>(out0 + (size_t)row * T_LEN);
  #pragma unroll
  for (int k = 0; k < 4; ++k) {
    float4 v = s4[tid + (k << 8)];
    *reinterpret_cast<float4*>(&A[4 * (tid + (k << 8))]) = v;
    o04[tid + (k << 8)] = v;  // out0 = x
  }
  __syncthreads();
  dwt_step(A, 4096, B, D1, 2051, tid); __syncthreads();
  dwt_step(B, 2051, A, D2, 1029, tid); __syncthreads();
  dwt_step(A, 1029, B, D3, 518, tid);  __syncthreads();
  dwt_step(B, 518, A4, D4, 262, tid);  __syncthreads();

  // std(a4), ddof=0 — numpy pairwise semantics, blocks computed in parallel
  if (tid < 3) {
    const float* p = A4 + (tid == 0 ? 0 : (tid == 1 ? 128 : 192));
    int n = (tid == 0 ? 128 : (tid == 1 ? 64 : 70));
    sb[tid] = np_pw_block(p, n);
  }
  __syncthreads();
  if (tid == 0) s_mu = __fadd_rn(sb[0], __fadd_rn(sb[1], sb[2])) / 262.0f;
  __syncthreads();
  float mu = s_mu;
  for (int i = tid; i < 262; i += 256) {
    float dv = __fsub_rn(A4[i], mu);
    SQ[i] = __fmul_rn(dv, dv);
  }
  __syncthreads();
  if (tid < 3) {
    const float* p = SQ + (tid == 0 ? 0 : (tid == 1 ? 128 : 192));
    int n = (tid == 0 ? 128 : (tid == 1 ? 64 : 70));
    sb[tid] = np_pw_block(p, n);
  }
  __syncthreads();
  if (tid == 0)
    s_sigma = __fsqrt_rn(__fadd_rn(sb[0], __fadd_rn(sb[1], sb[2])) / 262.0f);
  __syncthreads();
  float sigma = s_sigma;

  for (int v = 0; v < 2; ++v) {
    float thr = __fmul_rn((v == 0 ? 0.5f : 0.25f), sigma);
    for (int i = tid; i < 262; i += 256) {
      float c = A4[i];
      A[i] = (fabsf(c) < thr) ? 0.f : c;
    }
    __syncthreads();
    idwt_step(A, D4, 262, B, thr, tid);  __syncthreads();  // -> B[518]
    idwt_step(B, D3, 518, A, thr, tid);  __syncthreads();  // -> A[1030] (use 1029)
    idwt_step(A, D2, 1029, B, thr, tid); __syncthreads();  // -> B[2052] (use 2051)
    idwt_step(B, D1, 2051, A, thr, tid); __syncthreads();  // -> A[4096]
    float4* dst4 = reinterpret_cast<float4*>((v == 0 ? out1 : out4) + (size_t)row * T_LEN);
    #pragma unroll
    for (int k = 0; k < 4; ++k)
      dst4[tid + (k << 8)] = *reinterpret_cast<const float4*>(&A[4 * (tid + (k << 8))]);
    __syncthreads();
  }
}

// ---------------- fused spectral distortion + additive noise ----------------
// DIF forward (natural in) -> mask at bit-reversed index -> DIT inverse (natural out).
__global__ __launch_bounds__(256)
void distort_noise_kernel(const float* __restrict__ src, float* __restrict__ dst_d,
                          float* __restrict__ dst_n, int nod, int which, int wd) {
  __shared__ __align__(16) float2 FA[4096];
  __shared__ float2 TW[2048];
  __shared__ float red[256];
  const int row = blockIdx.x, tid = threadIdx.x;
  const int f0 = which ? g_params.f0_c : g_params.f0_d;
  const int af = which ? g_params.af_c : g_params.af_d;
  const int t0 = which ? g_params.t0_c : g_params.t0_d;
  const int at = which ? g_params.at_c : g_params.at_d;

  const float4* s4 = reinterpret_cast<const float4*>(src + (size_t)row * T_LEN);
  float4 v4[4];
  #pragma unroll
  for (int k = 0; k < 4; ++k) v4[k] = s4[tid + (k << 8)];

  float w[16];
  if (af) {
    for (int k = tid; k < 2048; k += 256) {
      float ang = (float)((double)k * -1.5339807878856412e-3);  // -pi/2048 * k
      float sn, cs;
      sincosf(ang, &sn, &cs);
      TW[k] = make_float2(cs, sn);
    }
    #pragma unroll
    for (int k = 0; k < 4; ++k) {
      int base = 4 * (tid + (k << 8));
      FA[base + 0] = make_float2(v4[k].x, 0.f);
      FA[base + 1] = make_float2(v4[k].y, 0.f);
      FA[base + 2] = make_float2(v4[k].z, 0.f);
      FA[base + 3] = make_float2(v4[k].w, 0.f);
    }
    __syncthreads();
    // forward DIF
    for (int lg = 12; lg >= 1; --lg) {
      int hs = lg - 1;
      for (int b = tid; b < 2048; b += 256) {
        int j = b & ((1 << hs) - 1);
        int i0 = ((b >> hs) << lg) + j;
        int i1 = i0 + (1 << hs);
        float2 u = FA[i0], t = FA[i1];
        FA[i0] = make_float2(u.x + t.x, u.y + t.y);
        float dx = u.x - t.x, dy = u.y - t.y;
        float2 tw = TW[j << (12 - lg)];
        FA[i1] = make_float2(dx * tw.x - dy * tw.y, dx * tw.y + dy * tw.x);
      }
      __syncthreads();
    }
    // frequency mask (spectrum is in bit-reversed order)
    for (int idx = tid; idx < 4096; idx += 256) {
      int kk = (int)(__brev((unsigned)idx) >> 20);
      if (kk >= f0 && kk < f0 + 409) { FA[idx].x *= 0.1f; FA[idx].y *= 0.1f; }
    }
    __syncthreads();
    // inverse DIT (conjugate twiddles), natural-order output
    for (int lg = 1; lg <= 12; ++lg) {
      int hs = lg - 1;
      for (int b = tid; b < 2048; b += 256) {
        int j = b & ((1 << hs) - 1);
        int i0 = ((b >> hs) << lg) + j;
        int i1 = i0 + (1 << hs);
        float2 u = FA[i0], t2 = FA[i1];
        float2 tw = TW[j << (12 - lg)];
        float tx = t2.x * tw.x + t2.y * tw.y;
        float ty = t2.y * tw.x - t2.x * tw.y;
        FA[i0] = make_float2(u.x + tx, u.y + ty);
        FA[i1] = make_float2(u.x - tx, u.y - ty);
      }
      __syncthreads();
    }
    #pragma unroll
    for (int k = 0; k < 4; ++k) {
      int base = 4 * (tid + (k << 8));
      w[4 * k + 0] = FA[base + 0].x * (1.0f / 4096.0f);
      w[4 * k + 1] = FA[base + 1].x * (1.0f / 4096.0f);
      w[4 * k + 2] = FA[base + 2].x * (1.0f / 4096.0f);
      w[4 * k + 3] = FA[base + 3].x * (1.0f / 4096.0f);
    }
  } else {
    #pragma unroll
    for (int k = 0; k < 4; ++k) {
      w[4 * k + 0] = v4[k].x; w[4 * k + 1] = v4[k].y;
      w[4 * k + 2] = v4[k].z; w[4 * k + 3] = v4[k].w;
    }
  }
  // time mask
  if (at) {
    #pragma unroll
    for (int i = 0; i < 16; ++i) {
      int col = 4 * (tid + ((i >> 2) << 8)) + (i & 3);
      if (col >= t0 && col < t0 + 204) w[i] *= 0.1f;
    }
  }
  if (wd) {
    float4* d4 = reinterpret_cast<float4*>(dst_d + (size_t)row * T_LEN);
    #pragma unroll
    for (int k = 0; k < 4; ++k)
      d4[tid + (k << 8)] = make_float4(w[4 * k], w[4 * k + 1], w[4 * k + 2], w[4 * k + 3]);
  }

  // ---- noise: sigma (ddof=1, tree reduction) over (nod ? distorted : x) ----
  float nv[16];
  #pragma unroll
  for (int i = 0; i < 16; ++i) {
    float q;
    if (nod) q = w[i];
    else {
      float4 vv = v4[i >> 2];
      q = (i & 3) == 0 ? vv.x : (i & 3) == 1 ? vv.y : (i & 3) == 2 ? vv.z : vv.w;
    }
    nv[i] = q;
  }
  float acc = 0.f;
  #pragma unroll
  for (int i = 0; i < 16; ++i) acc += nv[i];
  red[tid] = acc; __syncthreads();
  for (int o = 128; o > 0; o >>= 1) { if (tid < o) red[tid] += red[tid + o]; __syncthreads(); }
  float mu = red[0] * (1.0f / 4096.0f);
  __syncthreads();
  acc = 0.f;
  #pragma unroll
  for (int i = 0; i < 16; ++i) { float dv = nv[i] - mu; acc += dv * dv; }
  red[tid] = acc; __syncthreads();
  for (int o = 128; o > 0; o >>= 1) { if (tid < o) red[tid] += red[tid + o]; __syncthreads(); }
  float sigma = sqrtf(red[0] / 4095.0f);  // ddof=1

  uint32_t kx = which ? g_params.kcn_x : g_params.kn_x;
  uint32_t ky = which ? g_params.kcn_y : g_params.kn_y;
  float4* n4 = reinterpret_cast<float4*>(dst_n + (size_t)row * T_LEN);
  #pragma unroll
  for (int k = 0; k < 4; ++k) {
    float o[4];
    #pragma unroll
    for (int c = 0; c < 4; ++c) {
      uint32_t col = (uint32_t)(4 * (tid + (k << 8)) + c);
      uint32_t idx = ((uint32_t)row << 12) + col;
      float z = jax_normal_from_bits(jbits_elem(kx, ky, idx));
      o[c] = nv[4 * k + c] + __fmul_rn(__fmul_rn(z, 0.02f), sigma);
    }
    n4[tid + (k << 8)] = make_float4(o[0], o[1], o[2], o[3]);
  }
}

// ---------------- launcher ----------------
extern "C" void kernel_launch(void* const* d_in, const int* in_sizes, int n_in,
                              void* d_out, int out_size, void* d_ws, size_t ws_size,
                              hipStream_t stream) {
  const float* x = (const float*)d_in[0];
  float* out = (float*)d_out;
  float* o0 = out;
  float* o1 = out + (size_t)N_ELEM;
  float* o2 = out + 2 * (size_t)N_ELEM;
  float* o3 = out + 3 * (size_t)N_ELEM;
  float* o4 = out + 4 * (size_t)N_ELEM;

  hipLaunchKernelGGL(setup_rng_kernel, dim3(1), dim3(64), 0, stream);
  // out0 = x, out1 = compress(x,0.5), out4 = compress(x,0.25) [pre-distort]
  hipLaunchKernelGGL(wavelet_kernel, dim3(N_ROWS), dim3(256), 0, stream, x, o0, o1, o4);
  // out2 = distort(x, kd); out3 = x + noise(kn, std(x))   [x read once]
  hipLaunchKernelGGL(distort_noise_kernel, dim3(N_ROWS), dim3(256), 0, stream,
                     x, o2, o3, 0, 0, 1);
  // out4 = distort(out4, kcd) + noise(kcn, std(distorted))  [fused, in-register]
  hipLaunchKernelGGL(distort_noise_kernel, dim3(N_ROWS), dim3(256), 0, stream,
                     o4, o4, o4, 1, 1, 0);
}

// Round 8
// 333.188 us; speedup vs baseline: 2.7544x; 1.3629x over previous
//
#include <hip/hip_runtime.h>
#include <stdint.h>

#define T_LEN 4096
#define N_ROWS 4096
#define N_ELEM (4096u * 4096u)
#define PD(i) ((i) + ((i) >> 5))

// ---------------- wavelet filters (db4) ----------------
__constant__ float c_DEC_LO[8] = {
  -0.010597401785069032f, 0.0328830116668852f, 0.030841381835560764f,
  -0.18703481171909309f, -0.027983769416859854f, 0.6308807679298589f,
   0.7148465705529157f, 0.2303778133088965f };
__constant__ float c_DEC_HI[8] = {
  -0.2303778133088965f, 0.7148465705529157f, -0.6308807679298589f,
  -0.027983769416859854f, 0.18703481171909309f, 0.030841381835560764f,
  -0.0328830116668852f, -0.010597401785069032f };

#define RL0 0.2303778133088965f
#define RL1 0.7148465705529157f
#define RL2 0.6308807679298589f
#define RL3 (-0.027983769416859854f)
#define RL4 (-0.18703481171909309f)
#define RL5 0.030841381835560764f
#define RL6 0.0328830116668852f
#define RL7 (-0.010597401785069032f)
#define RH0 (-0.010597401785069032f)
#define RH1 (-0.0328830116668852f)
#define RH2 0.030841381835560764f
#define RH3 0.18703481171909309f
#define RH4 (-0.027983769416859854f)
#define RH5 (-0.6308807679298589f)
#define RH6 0.7148465705529157f
#define RH7 (-0.2303778133088965f)

// ---------------- Threefry-2x32 (host+device) ----------------
__host__ __device__ __forceinline__ uint32_t rotl32(uint32_t v, int r) {
  return (v << r) | (v >> (32 - r));
}

__host__ __device__ __forceinline__ void tf2x32(uint32_t k0, uint32_t k1,
                                                uint32_t c0, uint32_t c1,
                                                uint32_t& o0, uint32_t& o1) {
  uint32_t ks2 = k0 ^ k1 ^ 0x1BD11BDAu;
  uint32_t x0 = c0 + k0;
  uint32_t x1 = c1 + k1;
#define TFR(r) { x0 += x1; x1 = rotl32(x1, r); x1 ^= x0; }
  TFR(13) TFR(15) TFR(26) TFR(6)
  x0 += k1;  x1 += ks2 + 1u;
  TFR(17) TFR(29) TFR(16) TFR(24)
  x0 += ks2; x1 += k0 + 2u;
  TFR(13) TFR(15) TFR(26) TFR(6)
  x0 += k0;  x1 += k1 + 3u;
  TFR(17) TFR(29) TFR(16) TFR(24)
  x0 += k1;  x1 += ks2 + 4u;
  TFR(13) TFR(15) TFR(26) TFR(6)
  x0 += ks2; x1 += k0 + 5u;
#undef TFR
  o0 = x0; o1 = x1;
}

__host__ __device__ __forceinline__ uint32_t jbits_scalar(uint32_t kx, uint32_t ky) {
  uint32_t a, b; tf2x32(kx, ky, 0u, 0u, a, b);
  return a ^ b;
}

__device__ __forceinline__ uint32_t jbits_elem(uint32_t kx, uint32_t ky, uint32_t i) {
  uint32_t a, b; tf2x32(kx, ky, 0u, i, a, b); return a ^ b;
}

__host__ __device__ __forceinline__ float junif_scalar(uint32_t kx, uint32_t ky) {
  union { uint32_t u; float f; } cv;
  cv.u = (jbits_scalar(kx, ky) >> 9) | 0x3f800000u;
  return cv.f - 1.0f;
}

__host__ __device__ __forceinline__ void jsplit2(uint32_t kx, uint32_t ky, uint32_t* o) {
  tf2x32(kx, ky, 0u, 0u, o[0], o[1]);
  tf2x32(kx, ky, 0u, 1u, o[2], o[3]);
}

__host__ __device__ __forceinline__ void jsplit4(uint32_t kx, uint32_t ky, uint32_t* o) {
  tf2x32(kx, ky, 0u, 0u, o[0], o[1]);
  tf2x32(kx, ky, 0u, 1u, o[2], o[3]);
  tf2x32(kx, ky, 0u, 2u, o[4], o[5]);
  tf2x32(kx, ky, 0u, 3u, o[6], o[7]);
}

__host__ __device__ __forceinline__ int jrandint(uint32_t kx, uint32_t ky, uint32_t span) {
  uint32_t c[4];
  jsplit2(kx, ky, c);
  uint32_t hi = jbits_scalar(c[0], c[1]);
  uint32_t lo = jbits_scalar(c[2], c[3]);
  uint32_t mult = 65536u % span;
  mult = (mult * mult) % span;
  uint32_t off = ((hi % span) * mult + (lo % span)) % span;
  return (int)off;
}

__host__ __device__ void distort_params(uint32_t kx, uint32_t ky,
                                        int* f0, int* af, int* t0, int* at) {
  uint32_t q[8];
  jsplit4(kx, ky, q);
  *af = junif_scalar(q[0], q[1]) < 0.3f;
  *f0 = jrandint(q[2], q[3], 3687u);
  *at = junif_scalar(q[4], q[5]) < 0.3f;
  *t0 = jrandint(q[6], q[7], 3892u);
}

__device__ __forceinline__ float erfinv32(float x) {
  float w = -log1pf(-x * x);
  float p;
  if (w < 5.0f) {
    w = w - 2.5f;
    p = 2.81022636e-08f;
    p = fmaf(p, w, 3.43273939e-07f);
    p = fmaf(p, w, -3.5233877e-06f);
    p = fmaf(p, w, -4.39150654e-06f);
    p = fmaf(p, w, 0.00021858087f);
    p = fmaf(p, w, -0.00125372503f);
    p = fmaf(p, w, -0.00417768164f);
    p = fmaf(p, w, 0.246640727f);
    p = fmaf(p, w, 1.50140941f);
  } else {
    w = sqrtf(w) - 3.0f;
    p = -0.000200214257f;
    p = fmaf(p, w, 0.000100950558f);
    p = fmaf(p, w, 0.00134934322f);
    p = fmaf(p, w, -0.00367342844f);
    p = fmaf(p, w, 0.00573950773f);
    p = fmaf(p, w, -0.0076224613f);
    p = fmaf(p, w, 0.00943887047f);
    p = fmaf(p, w, 1.00167406f);
    p = fmaf(p, w, 2.83297682f);
  }
  return p * x;
}

__device__ __forceinline__ float jax_normal_from_bits(uint32_t bits) {
  union { uint32_t u; float f; } cv;
  cv.u = (bits >> 9) | 0x3f800000u;
  float f = cv.f - 1.0f;
  const float lo = -0.99999994f;
  float u = __fadd_rn(__fmul_rn(f, 2.0f), lo);
  u = fmaxf(lo, u);
  return 1.41421356f * erfinv32(u);
}

// numpy tree-of-8 sum
__device__ __forceinline__ float tree8(const float* p) {
  return __fadd_rn(
      __fadd_rn(__fadd_rn(p[0], p[1]), __fadd_rn(p[2], p[3])),
      __fadd_rn(__fadd_rn(p[4], p[5]), __fadd_rn(p[6], p[7])));
}

// ---------------- wavelet steps (bit-exact vs round 6/7) ----------------
__device__ void dwt_step(const float* a, int n, float* oa, float* od, int nOut, int tid) {
  int iHi = (n - 2) >> 1;
  for (int i = tid; i < nOut; i += 256) {
    int base = 2 * i - 6;
    float pa[8], pd[8];
    if (i >= 3 && i <= iHi) {
      #pragma unroll
      for (int j = 0; j < 8; ++j) {
        float xv = a[base + j];
        pa[j] = __fmul_rn(c_DEC_LO[7 - j], xv);
        pd[j] = __fmul_rn(c_DEC_HI[7 - j], xv);
      }
    } else {
      #pragma unroll
      for (int j = 0; j < 8; ++j) {
        int q = base + j;
        q = (q < 0) ? (-q - 1) : ((q >= n) ? (2 * n - 1 - q) : q);
        float xv = a[q];
        pa[j] = __fmul_rn(c_DEC_LO[7 - j], xv);
        pd[j] = __fmul_rn(c_DEC_HI[7 - j], xv);
      }
    }
    oa[i] = tree8(pa);
    od[i] = tree8(pd);
  }
}

// parity-split idwt; thresholds d always, a only when trA (level-4 input).
__device__ void idwt_step(const float* __restrict__ a, const float* __restrict__ d,
                          int m, float* __restrict__ out, int nOut, float thr,
                          bool trA, int tid) {
  for (int t = tid; t < nOut; t += 256) {
    int odd = t & 1;
    int h0 = (t - odd) >> 1;
    float a0 = a[h0], a1 = a[h0 + 1], a2 = a[h0 + 2], a3 = a[h0 + 3];
    if (trA) {
      a0 = (fabsf(a0) < thr) ? 0.f : a0;
      a1 = (fabsf(a1) < thr) ? 0.f : a1;
      a2 = (fabsf(a2) < thr) ? 0.f : a2;
      a3 = (fabsf(a3) < thr) ? 0.f : a3;
    }
    float d0 = d[h0], d1 = d[h0 + 1], d2 = d[h0 + 2], d3 = d[h0 + 3];
    d0 = (fabsf(d0) < thr) ? 0.f : d0;
    d1 = (fabsf(d1) < thr) ? 0.f : d1;
    d2 = (fabsf(d2) < thr) ? 0.f : d2;
    d3 = (fabsf(d3) < thr) ? 0.f : d3;
    float cl0 = odd ? RL7 : RL6, cl1 = odd ? RL5 : RL4;
    float cl2 = odd ? RL3 : RL2, cl3 = odd ? RL1 : RL0;
    float ch0 = odd ? RH7 : RH6, ch1 = odd ? RH5 : RH4;
    float ch2 = odd ? RH3 : RH2, ch3 = odd ? RH1 : RH0;
    float sa = __fadd_rn(__fadd_rn(__fmul_rn(cl0, a0), __fmul_rn(cl1, a1)),
                         __fadd_rn(__fmul_rn(cl2, a2), __fmul_rn(cl3, a3)));
    float sd = __fadd_rn(__fadd_rn(__fmul_rn(ch0, d0), __fmul_rn(ch1, d1)),
                         __fadd_rn(__fmul_rn(ch2, d2), __fmul_rn(ch3, d3)));
    out[t] = __fadd_rn(sa, sd);
  }
}

// parallel numpy-pairwise sum over 262 elements in src; partials in pbuf[24].
// Returns (via *res on tid==0's write to resSlot) sum with exact np order.
__device__ void np_pw262_partials(const float* src, float* pbuf, int tid) {
  if (tid < 24) {
    int blk = tid >> 3, k = tid & 7;
    const float* base = src + (blk == 0 ? 0 : (blk == 1 ? 128 : 192));
    int iters = (blk == 0 ? 16 : 8);
    float r = base[k];
    for (int it = 1; it < iters; ++it) r = __fadd_rn(r, base[8 * it + k]);
    pbuf[tid] = r;
  }
}

__device__ float np_pw262_combine(const float* src, const float* pbuf) {
  float b0 = tree8(pbuf + 0);
  float b1 = tree8(pbuf + 8);
  float b2 = tree8(pbuf + 16);
  for (int i = 256; i < 262; ++i) b2 = __fadd_rn(b2, src[i]);
  return __fadd_rn(b0, __fadd_rn(b1, b2));
}

// ---------------- wavelet kernel (writes o0, o1, o4[; fused mask+noise]) ----
__global__ __launch_bounds__(256)
void wavelet_kernel(const float* __restrict__ x, float* __restrict__ out0,
                    float* __restrict__ out1, float* __restrict__ out4,
                    int fuse, int at_c, int t0_c, uint32_t kcx, uint32_t kcy) {
  extern __shared__ float smem[];
  float* A  = smem;              // 4096
  float* B  = smem + 4096;       // 2051
  float* D1 = smem + 6147;       // 2051
  float* D2 = smem + 8198;       // 1029
  float* D3 = smem + 9227;       // 518
  float* D4 = smem + 9745;       // 262
  float* SC = smem + 10007;      // 2 (mu, sigma)
  float* Bp = B + 512;           // 24 partials (scratch)
  const int row = blockIdx.x, tid = threadIdx.x;
  const float4* s4 = reinterpret_cast<const float4*>(x + (size_t)row * T_LEN);
  float4* o04 = reinterpret_cast<float4*>(out0 + (size_t)row * T_LEN);
  #pragma unroll
  for (int k = 0; k < 4; ++k) {
    float4 v = s4[tid + (k << 8)];
    *reinterpret_cast<float4*>(&A[4 * (tid + (k << 8))]) = v;
    o04[tid + (k << 8)] = v;
  }
  __syncthreads();
  dwt_step(A, 4096, B, D1, 2051, tid); __syncthreads();
  dwt_step(B, 2051, A, D2, 1029, tid); __syncthreads();
  dwt_step(A, 1029, B, D3, 518, tid);  __syncthreads();
  dwt_step(B, 518, A, D4, 262, tid);   __syncthreads();  // a4 -> A[0:262)

  // sigma(a4), ddof=0, exact numpy pairwise order
  np_pw262_partials(A, Bp, tid);
  __syncthreads();
  if (tid == 0) SC[0] = np_pw262_combine(A, Bp) / 262.0f;
  __syncthreads();
  float mu = SC[0];
  for (int i = tid; i < 262; i += 256) {
    float dv = __fsub_rn(A[i], mu);
    B[i] = __fmul_rn(dv, dv);   // SQ overlay in B
  }
  __syncthreads();
  np_pw262_partials(B, Bp, tid);
  __syncthreads();
  if (tid == 0) SC[1] = __fsqrt_rn(np_pw262_combine(B, Bp) / 262.0f);
  __syncthreads();
  float sigma = SC[1];

  // stash a4 in registers (A gets clobbered by idwt chain)
  float ra0 = A[tid];
  float ra1 = (tid < 6) ? A[256 + tid] : 0.f;

  #pragma unroll
  for (int v = 0; v < 2; ++v) {
    if (v == 1) {
      __syncthreads();
      A[tid] = ra0;
      if (tid < 6) A[256 + tid] = ra1;
      __syncthreads();
    }
    float thr = __fmul_rn((v == 0 ? 0.5f : 0.25f), sigma);
    idwt_step(A, D4, 262, B, 518, thr, true, tid);    __syncthreads();
    idwt_step(B, D3, 518, A, 1029, thr, false, tid);  __syncthreads();
    idwt_step(A, D2, 1029, B, 2051, thr, false, tid); __syncthreads();
    idwt_step(B, D1, 2051, A, 4096, thr, false, tid); __syncthreads();
    if (v == 0) {
      float4* dst4 = reinterpret_cast<float4*>(out1 + (size_t)row * T_LEN);
      #pragma unroll
      for (int k = 0; k < 4; ++k)
        dst4[tid + (k << 8)] = *reinterpret_cast<const float4*>(&A[4 * (tid + (k << 8))]);
    }
  }

  float4* dst4 = reinterpret_cast<float4*>(out4 + (size_t)row * T_LEN);
  if (!fuse) {
    #pragma unroll
    for (int k = 0; k < 4; ++k)
      dst4[tid + (k << 8)] = *reinterpret_cast<const float4*>(&A[4 * (tid + (k << 8))]);
    return;
  }

  // fused (af_c == false): time-mask + additive noise on compress(0.25)
  float w[16];
  #pragma unroll
  for (int k = 0; k < 4; ++k) {
    float4 vv = *reinterpret_cast<const float4*>(&A[4 * (tid + (k << 8))]);
    w[4 * k + 0] = vv.x; w[4 * k + 1] = vv.y; w[4 * k + 2] = vv.z; w[4 * k + 3] = vv.w;
  }
  if (at_c) {
    #pragma unroll
    for (int i = 0; i < 16; ++i) {
      int col = 4 * (tid + ((i >> 2) << 8)) + (i & 3);
      if (col >= t0_c && col < t0_c + 204) w[i] *= 0.1f;
    }
  }
  __syncthreads();
  float* red = B;
  float acc = 0.f;
  #pragma unroll
  for (int i = 0; i < 16; ++i) acc += w[i];
  red[tid] = acc; __syncthreads();
  for (int o = 128; o > 0; o >>= 1) { if (tid < o) red[tid] += red[tid + o]; __syncthreads(); }
  float nmu = red[0] * (1.0f / 4096.0f);
  __syncthreads();
  acc = 0.f;
  #pragma unroll
  for (int i = 0; i < 16; ++i) { float dv = w[i] - nmu; acc += dv * dv; }
  red[tid] = acc; __syncthreads();
  for (int o = 128; o > 0; o >>= 1) { if (tid < o) red[tid] += red[tid + o]; __syncthreads(); }
  float nsig = sqrtf(red[0] / 4095.0f);

  #pragma unroll
  for (int k = 0; k < 4; ++k) {
    float o[4];
    #pragma unroll
    for (int c = 0; c < 4; ++c) {
      uint32_t col = (uint32_t)(4 * (tid + (k << 8)) + c);
      uint32_t idx = ((uint32_t)row << 12) + col;
      float z = jax_normal_from_bits(jbits_elem(kcx, kcy, idx));
      o[c] = w[4 * k + c] + __fmul_rn(__fmul_rn(z, 0.02f), nsig);
    }
    dst4[tid + (k << 8)] = make_float4(o[0], o[1], o[2], o[3]);
  }
}

// ---------------- radix-4 FFT distort + noise ----------------
__constant__ int c_STW_OFF[6] = {0, 1024, 1280, 1344, 1360, 1364};

__global__ __launch_bounds__(256)
void distort_noise_kernel(const float* __restrict__ src, float* __restrict__ dst_d,
                          float* __restrict__ dst_n,
                          int af, int f0, int at, int t0, int nod, int wd,
                          uint32_t kx, uint32_t ky) {
  extern __shared__ float smem[];
  float* RE = smem;                    // 4224 (padded 4096)
  float* IM = smem + 4224;             // 4224
  float2* STW = (float2*)(smem + 8448);// 1365 float2
  const int row = blockIdx.x, tid = threadIdx.x;

  const float4* s4 = reinterpret_cast<const float4*>(src + (size_t)row * T_LEN);
  float4 v4[4];
  #pragma unroll
  for (int k = 0; k < 4; ++k) v4[k] = s4[tid + (k << 8)];

  float w[16];
  if (af) {
    // stage-sequential twiddle table: w = exp(-i*pi*e/2048), e = j*4^s < 1024
    for (int t = tid; t < 1365; t += 256) {
      int s, j;
      if (t < 1024) { s = 0; j = t; }
      else if (t < 1280) { s = 1; j = t - 1024; }
      else if (t < 1344) { s = 2; j = t - 1280; }
      else if (t < 1360) { s = 3; j = t - 1344; }
      else if (t < 1364) { s = 4; j = t - 1360; }
      else { s = 5; j = 0; }
      int e = j << (2 * s);
      float ang = (float)e * (-1.5339807878856412e-3f);  // -pi/2048
      float sn, cs;
      __sincosf(ang, &sn, &cs);
      STW[t] = make_float2(cs, sn);
    }
    #pragma unroll
    for (int k = 0; k < 4; ++k) {
      int p = 4 * (tid + (k << 8));
      RE[PD(p + 0)] = v4[k].x; IM[PD(p + 0)] = 0.f;
      RE[PD(p + 1)] = v4[k].y; IM[PD(p + 1)] = 0.f;
      RE[PD(p + 2)] = v4[k].z; IM[PD(p + 2)] = 0.f;
      RE[PD(p + 3)] = v4[k].w; IM[PD(p + 3)] = 0.f;
    }
    __syncthreads();
    // forward radix-4 DIF
    for (int s = 0; s < 6; ++s) {
      int Lsh = 12 - 2 * s, Qsh = Lsh - 2, Qm = (1 << Qsh) - 1, off = c_STW_OFF[s];
      for (int b = tid; b < 1024; b += 256) {
        int j = b & Qm, g = b >> Qsh;
        int i0 = (g << Lsh) + j;
        int i1 = i0 + (1 << Qsh), i2 = i1 + (1 << Qsh), i3 = i2 + (1 << Qsh);
        float x0r = RE[PD(i0)], x0i = IM[PD(i0)];
        float x1r = RE[PD(i1)], x1i = IM[PD(i1)];
        float x2r = RE[PD(i2)], x2i = IM[PD(i2)];
        float x3r = RE[PD(i3)], x3i = IM[PD(i3)];
        float t0r = x0r + x2r, t0i = x0i + x2i;
        float t1r = x0r - x2r, t1i = x0i - x2i;
        float t2r = x1r + x3r, t2i = x1i + x3i;
        float t3r = x1r - x3r, t3i = x1i - x3i;
        float2 w1 = STW[off + j];
        float c1 = w1.x, s1 = w1.y;
        float c2 = c1 * c1 - s1 * s1, s2 = 2.f * c1 * s1;
        float c3 = c1 * c2 - s1 * s2, s3 = c1 * s2 + s1 * c2;
        RE[PD(i0)] = t0r + t2r; IM[PD(i0)] = t0i + t2i;
        float u1r = t1r + t3i, u1i = t1i - t3r;            // t1 - i*t3
        RE[PD(i1)] = u1r * c1 - u1i * s1; IM[PD(i1)] = u1r * s1 + u1i * c1;
        float u2r = t0r - t2r, u2i = t0i - t2i;
        RE[PD(i2)] = u2r * c2 - u2i * s2; IM[PD(i2)] = u2r * s2 + u2i * c2;
        float u3r = t1r - t3i, u3i = t1i + t3r;            // t1 + i*t3
        RE[PD(i3)] = u3r * c3 - u3i * s3; IM[PD(i3)] = u3r * s3 + u3i * c3;
      }
      __syncthreads();
    }
    // mask (spectrum in base-4 digit-reversed order)
    for (int p = tid; p < 4096; p += 256) {
      uint32_t rb = __brev((uint32_t)p) >> 20;
      int kk = (int)(((rb & 0x555u) << 1) | ((rb >> 1) & 0x555u));
      if (kk >= f0 && kk < f0 + 409) { RE[PD(p)] *= 0.1f; IM[PD(p)] *= 0.1f; }
    }
    __syncthreads();
    // inverse radix-4 DIT (conjugate twiddles), natural-order out
    for (int s = 5; s >= 0; --s) {
      int Lsh = 12 - 2 * s, Qsh = Lsh - 2, Qm = (1 << Qsh) - 1, off = c_STW_OFF[s];
      for (int b = tid; b < 1024; b += 256) {
        int j = b & Qm, g = b >> Qsh;
        int i0 = (g << Lsh) + j;
        int i1 = i0 + (1 << Qsh), i2 = i1 + (1 << Qsh), i3 = i2 + (1 << Qsh);
        float y0r = RE[PD(i0)], y0i = IM[PD(i0)];
        float y1r = RE[PD(i1)], y1i = IM[PD(i1)];
        float y2r = RE[PD(i2)], y2i = IM[PD(i2)];
        float y3r = RE[PD(i3)], y3i = IM[PD(i3)];
        float2 w1 = STW[off + j];
        float c1 = w1.x, s1 = -w1.y;                       // conj
        float c2 = c1 * c1 - s1 * s1, s2 = 2.f * c1 * s1;
        float c3 = c1 * c2 - s1 * s2, s3 = c1 * s2 + s1 * c2;
        float z1r = y1r * c1 - y1i * s1, z1i = y1r * s1 + y1i * c1;
        float z2r = y2r * c2 - y2i * s2, z2i = y2r * s2 + y2i * c2;
        float z3r = y3r * c3 - y3i * s3, z3i = y3r * s3 + y3i * c3;
        float u0r = y0r + z2r, u0i = y0i + z2i;
        float u2r = y0r - z2r, u2i = y0i - z2i;
        float u1r = z1r + z3r, u1i = z1i + z3i;
        float u3r = z3i - z1i, u3i = z1r - z3r;            // i*(z1-z3)
        RE[PD(i0)] = u0r + u1r; IM[PD(i0)] = u0i + u1i;
        RE[PD(i1)] = u2r + u3r; IM[PD(i1)] = u2i + u3i;
        RE[PD(i2)] = u0r - u1r; IM[PD(i2)] = u0i - u1i;
        RE[PD(i3)] = u2r - u3r; IM[PD(i3)] = u2i - u3i;
      }
      __syncthreads();
    }
    #pragma unroll
    for (int k = 0; k < 4; ++k) {
      int p = 4 * (tid + (k << 8));
      w[4 * k + 0] = RE[PD(p + 0)] * (1.0f / 4096.0f);
      w[4 * k + 1] = RE[PD(p + 1)] * (1.0f / 4096.0f);
      w[4 * k + 2] = RE[PD(p + 2)] * (1.0f / 4096.0f);
      w[4 * k + 3] = RE[PD(p + 3)] * (1.0f / 4096.0f);
    }
    __syncthreads();
  } else {
    #pragma unroll
    for (int k = 0; k < 4; ++k) {
      w[4 * k + 0] = v4[k].x; w[4 * k + 1] = v4[k].y;
      w[4 * k + 2] = v4[k].z; w[4 * k + 3] = v4[k].w;
    }
  }
  if (at) {
    #pragma unroll
    for (int i = 0; i < 16; ++i) {
      int col = 4 * (tid + ((i >> 2) << 8)) + (i & 3);
      if (col >= t0 && col < t0 + 204) w[i] *= 0.1f;
    }
  }
  if (wd) {
    float4* d4 = reinterpret_cast<float4*>(dst_d + (size_t)row * T_LEN);
    #pragma unroll
    for (int k = 0; k < 4; ++k)
      d4[tid + (k << 8)] = make_float4(w[4 * k], w[4 * k + 1], w[4 * k + 2], w[4 * k + 3]);
  }

  // noise: sigma ddof=1 over (nod ? distorted : x)
  float nv[16];
  #pragma unroll
  for (int i = 0; i < 16; ++i) {
    float q;
    if (nod) q = w[i];
    else {
      float4 vv = v4[i >> 2];
      q = (i & 3) == 0 ? vv.x : (i & 3) == 1 ? vv.y : (i & 3) == 2 ? vv.z : vv.w;
    }
    nv[i] = q;
  }
  float* red = smem;
  float acc = 0.f;
  #pragma unroll
  for (int i = 0; i < 16; ++i) acc += nv[i];
  red[tid] = acc; __syncthreads();
  for (int o = 128; o > 0; o >>= 1) { if (tid < o) red[tid] += red[tid + o]; __syncthreads(); }
  float mu = red[0] * (1.0f / 4096.0f);
  __syncthreads();
  acc = 0.f;
  #pragma unroll
  for (int i = 0; i < 16; ++i) { float dv = nv[i] - mu; acc += dv * dv; }
  red[tid] = acc; __syncthreads();
  for (int o = 128; o > 0; o >>= 1) { if (tid < o) red[tid] += red[tid + o]; __syncthreads(); }
  float sigma = sqrtf(red[0] / 4095.0f);

  float4* n4 = reinterpret_cast<float4*>(dst_n + (size_t)row * T_LEN);
  #pragma unroll
  for (int k = 0; k < 4; ++k) {
    float o[4];
    #pragma unroll
    for (int c = 0; c < 4; ++c) {
      uint32_t col = (uint32_t)(4 * (tid + (k << 8)) + c);
      uint32_t idx = ((uint32_t)row << 12) + col;
      float z = jax_normal_from_bits(jbits_elem(kx, ky, idx));
      o[c] = nv[4 * k + c] + __fmul_rn(__fmul_rn(z, 0.02f), sigma);
    }
    n4[tid + (k << 8)] = make_float4(o[0], o[1], o[2], o[3]);
  }
}

// ---------------- launcher (params computed host-side, deterministic) -------
extern "C" void kernel_launch(void* const* d_in, const int* in_sizes, int n_in,
                              void* d_out, int out_size, void* d_ws, size_t ws_size,
                              hipStream_t stream) {
  const float* x = (const float*)d_in[0];
  float* out = (float*)d_out;
  float* o0 = out;
  float* o1 = out + (size_t)N_ELEM;
  float* o2 = out + 2 * (size_t)N_ELEM;
  float* o3 = out + 3 * (size_t)N_ELEM;
  float* o4 = out + 4 * (size_t)N_ELEM;

  uint32_t r[8];
  jsplit4(0u, 42u, r);  // kd, kn, kcd, kcn
  int f0d, afd, t0d, atd, f0c, afc, t0c, atc;
  distort_params(r[0], r[1], &f0d, &afd, &t0d, &atd);
  distort_params(r[4], r[5], &f0c, &afc, &t0c, &atc);

  const size_t WAVE_LDS = 10009u * 4u;   // 40036 B -> 4 blocks/CU
  const size_t FFT_LDS  = 11178u * 4u;   // 44712 B

  hipLaunchKernelGGL(wavelet_kernel, dim3(N_ROWS), dim3(256), WAVE_LDS, stream,
                     x, o0, o1, o4, afc ? 0 : 1, atc, t0c, r[6], r[7]);
  hipLaunchKernelGGL(distort_noise_kernel, dim3(N_ROWS), dim3(256),
                     afd ? FFT_LDS : 1024, stream,
                     x, o2, o3, afd, f0d, atd, t0d, 0, 1, r[2], r[3]);
  if (afc) {
    hipLaunchKernelGGL(distort_noise_kernel, dim3(N_ROWS), dim3(256), FFT_LDS, stream,
                       o4, o4, o4, 1, f0c, atc, t0c, 1, 0, r[6], r[7]);
  }
}